// Round 1
// baseline (566.241 us; speedup 1.0000x reference)
//
#include <hip/hip_runtime.h>
#include <hip/hip_fp16.h>

#define SLOPE 0.2f

// ---------------------------------------------------------------------------
// attn = feat_rel @ W_rel + b_rel   (1 block, 256 threads, one col each)
// ---------------------------------------------------------------------------
__global__ void attn_kernel(const float* __restrict__ feat_rel,
                            const float* __restrict__ W_rel,
                            const float* __restrict__ b_rel,
                            float* __restrict__ attn) {
    int j = threadIdx.x;            // 0..255
    float acc = b_rel[j];
    for (int d = 0; d < 128; ++d)
        acc = fmaf(feat_rel[d], W_rel[d * 256 + j], acc);
    attn[j] = acc;
}

// ---------------------------------------------------------------------------
// Fused GEMM + per-head attention-scalar epilogue.
// Block = 256 threads, computes a 64-row x 128-col tile of f = feat@W + b.
// Thread t: rt = t>>4 (4 rows rt*4..), ct = t&15 (8 cols ct*8..): 4x8 microtile.
// Writes f (fp16, optional) and e[row][head] = sum_d f[row][h*16+d]*attn[h*32+attn_off+d].
// ---------------------------------------------------------------------------
__global__ __launch_bounds__(256) void gemm_el_kernel(
    const float* __restrict__ feat, const float* __restrict__ W,
    const float* __restrict__ bias, const float* __restrict__ attn,
    int attn_off, __half* __restrict__ f_out, float* __restrict__ e_out,
    int M)
{
    __shared__ float sA[64][68];    // [k][row], padded stride 68 (16B-aligned, bank-shifted)
    __shared__ float sW[64][128];   // [k][col]

    int t  = threadIdx.x;
    int rt = t >> 4;
    int ct = t & 15;
    int row0 = blockIdx.x * 64;

    float acc[4][8];
#pragma unroll
    for (int r = 0; r < 4; ++r)
#pragma unroll
        for (int j = 0; j < 8; ++j) acc[r][j] = 0.f;

    for (int kc = 0; kc < 2; ++kc) {
        int k0 = kc * 64;
        // stage A tile (64 rows x 64 k), transposed into sA[k][row]
        {
            int rr = t >> 4;        // 0..15
            int k4 = t & 15;        // float4 index within the 64-k chunk
#pragma unroll
            for (int i = 0; i < 4; ++i) {
                int row = rr + i * 16;
                int grow = row0 + row;
                float4 v = {0.f, 0.f, 0.f, 0.f};
                if (grow < M)
                    v = *(const float4*)(feat + (size_t)grow * 128 + k0 + k4 * 4);
                sA[k4 * 4 + 0][row] = v.x;
                sA[k4 * 4 + 1][row] = v.y;
                sA[k4 * 4 + 2][row] = v.z;
                sA[k4 * 4 + 3][row] = v.w;
            }
        }
        // stage W chunk (64 k x 128 cols)
        {
#pragma unroll
            for (int i = 0; i < 8; ++i) {
                int idx = t + i * 256;      // 0..2047 float4s
                int k = idx >> 5, j4 = idx & 31;
                *(float4*)&sW[k][j4 * 4] =
                    *(const float4*)(W + (size_t)(k0 + k) * 128 + j4 * 4);
            }
        }
        __syncthreads();
#pragma unroll 4
        for (int kk = 0; kk < 64; ++kk) {
            float4 a  = *(const float4*)&sA[kk][rt * 4];
            float4 b0 = *(const float4*)&sW[kk][ct * 8];
            float4 b1 = *(const float4*)&sW[kk][ct * 8 + 4];
            float av[4]  = {a.x, a.y, a.z, a.w};
            float bv[8]  = {b0.x, b0.y, b0.z, b0.w, b1.x, b1.y, b1.z, b1.w};
#pragma unroll
            for (int r = 0; r < 4; ++r)
#pragma unroll
                for (int j = 0; j < 8; ++j)
                    acc[r][j] = fmaf(av[r], bv[j], acc[r][j]);
        }
        __syncthreads();
    }

    // epilogue: bias, attention partial dot, fp16 store
    int h    = ct >> 1;             // head (16 cols per head, 8 cols per thread)
    int doff = (ct & 1) * 8;        // offset within head
    float bv[8], av[8];
#pragma unroll
    for (int j = 0; j < 8; ++j) {
        bv[j] = bias[ct * 8 + j];
        av[j] = attn[h * 32 + attn_off + doff + j];
    }
#pragma unroll
    for (int r = 0; r < 4; ++r) {
        int grow = row0 + rt * 4 + r;
        float part = 0.f;
#pragma unroll
        for (int j = 0; j < 8; ++j) {
            float v = acc[r][j] + bv[j];
            acc[r][j] = v;
            part = fmaf(v, av[j], part);
        }
        part += __shfl_xor(part, 1);    // combine the 2 col-threads of this head
        if (grow < M) {
            if (f_out) {
                union { __half hh[8]; float4 v4; } pk;
#pragma unroll
                for (int j = 0; j < 8; ++j) pk.hh[j] = __float2half(acc[r][j]);
                *(float4*)(f_out + (size_t)grow * 128 + ct * 8) = pk.v4;
            }
            if ((ct & 1) == 0)
                e_out[(size_t)grow * 8 + h] = part;
        }
    }
}

// ---------------------------------------------------------------------------
// CSR build
// ---------------------------------------------------------------------------
__global__ void degree_kernel(const int* __restrict__ dst_idx,
                              int* __restrict__ deg, int ne) {
    int e = blockIdx.x * 256 + threadIdx.x;
    if (e < ne) atomicAdd(&deg[dst_idx[e]], 1);
}

__global__ void scan1(const int* __restrict__ deg, int* __restrict__ excl,
                      int* __restrict__ bsum, int n) {
    __shared__ int tmp[256];
    int t = threadIdx.x;
    int i = blockIdx.x * 256 + t;
    int v = (i < n) ? deg[i] : 0;
    tmp[t] = v;
    __syncthreads();
    for (int off = 1; off < 256; off <<= 1) {
        int x = 0;
        if (t >= off) x = tmp[t - off];
        __syncthreads();
        tmp[t] += x;
        __syncthreads();
    }
    if (i < n) excl[i] = tmp[t] - v;
    if (t == 255) bsum[blockIdx.x] = tmp[255];
}

__global__ void scan2(int* __restrict__ bsum, int nb) {
    __shared__ int tmp[512];
    int t = threadIdx.x;
    int v = (t < nb) ? bsum[t] : 0;
    tmp[t] = v;
    __syncthreads();
    for (int off = 1; off < 512; off <<= 1) {
        int x = 0;
        if (t >= off) x = tmp[t - off];
        __syncthreads();
        tmp[t] += x;
        __syncthreads();
    }
    if (t < nb) bsum[t] = tmp[t] - v;   // exclusive block offsets
}

__global__ void scan3(const int* __restrict__ excl, const int* __restrict__ bsum,
                      int* __restrict__ roff, int n) {
    int i = blockIdx.x * 256 + threadIdx.x;
    if (i < n) roff[i] = excl[i] + bsum[blockIdx.x];
}

__global__ void fill_kernel(const int* __restrict__ src_idx,
                            const int* __restrict__ dst_idx,
                            const int* __restrict__ roff, int* __restrict__ cur,
                            int* __restrict__ csr, int ne) {
    int e = blockIdx.x * 256 + threadIdx.x;
    if (e < ne) {
        int d = dst_idx[e];
        int p = roff[d] + atomicAdd(&cur[d], 1);
        csr[p] = src_idx[e];
    }
}

// ---------------------------------------------------------------------------
// Aggregation: one wave per dst node. lane owns dims 2l,2l+1; head = l>>3.
// out[dst] = sum_e w_e * fs[src_e] / sum_e w_e   (== edge_softmax + u_mul_e + sum)
// ---------------------------------------------------------------------------
__global__ __launch_bounds__(256) void agg_kernel(
    const __half* __restrict__ fs, const float* __restrict__ el,
    const float* __restrict__ er, const int* __restrict__ roff,
    const int* __restrict__ deg, const int* __restrict__ csr,
    float* __restrict__ out, int n)
{
    int node = blockIdx.x * 4 + (threadIdx.x >> 6);
    if (node >= n) return;
    int lane = threadIdx.x & 63;
    int h = lane >> 3;
    float erk = er[(size_t)node * 8 + h];
    int start = roff[node];
    int d = deg[node];

    float accx = 0.f, accy = 0.f, wsum = 0.f;
    int scur = (d > 0) ? csr[start] : 0;
    for (int i = 0; i < d; ++i) {
        int snext = (i + 1 < d) ? csr[start + i + 1] : 0;  // prefetch
        float e = el[(size_t)scur * 8 + h] + erk;
        e = (e < 0.f) ? SLOPE * e : e;
        float wgt = __expf(e);
        __half2 f2 = *(const __half2*)(fs + (size_t)scur * 128 + 2 * lane);
        float2 ff = __half22float2(f2);
        accx = fmaf(wgt, ff.x, accx);
        accy = fmaf(wgt, ff.y, accy);
        wsum += wgt;
        scur = snext;
    }
    float inv = (d > 0) ? 1.0f / wsum : 0.f;
    float2 o;
    o.x = accx * inv;
    o.y = accy * inv;
    *(float2*)(out + (size_t)node * 128 + 2 * lane) = o;
}

// ---------------------------------------------------------------------------
extern "C" void kernel_launch(void* const* d_in, const int* in_sizes, int n_in,
                              void* d_out, int out_size, void* d_ws, size_t ws_size,
                              hipStream_t stream) {
    const float* feat_src = (const float*)d_in[0];
    const float* feat_dst = (const float*)d_in[1];
    const float* feat_rel = (const float*)d_in[2];
    const float* W_src    = (const float*)d_in[3];
    const float* b_src    = (const float*)d_in[4];
    const float* W_dst    = (const float*)d_in[5];
    const float* b_dst    = (const float*)d_in[6];
    const float* W_rel    = (const float*)d_in[7];
    const float* b_rel    = (const float*)d_in[8];
    const int*   src_idx  = (const int*)d_in[9];
    const int*   dst_idx  = (const int*)d_in[10];
    float* out = (float*)d_out;

    int n_src = in_sizes[0] / 128;
    int n_dst = in_sizes[1] / 128;
    int ne    = in_sizes[9];

    char* w = (char*)d_ws;
    auto alloc = [&](size_t b) { char* p = w; w += (b + 255) & ~(size_t)255; return p; };
    __half* fs   = (__half*)alloc((size_t)n_src * 128 * 2);
    float*  el   = (float*)alloc((size_t)n_src * 8 * 4);
    float*  er   = (float*)alloc((size_t)n_dst * 8 * 4);
    float*  attn = (float*)alloc(256 * 4);
    int*    deg  = (int*)alloc((size_t)n_dst * 4);
    int*    cur  = (int*)alloc((size_t)n_dst * 4);
    int*    excl = (int*)alloc((size_t)n_dst * 4);
    int*    bsum = (int*)alloc(512 * 4);
    int*    roff = (int*)alloc((size_t)n_dst * 4);
    int*    csr  = (int*)alloc((size_t)ne * 4);

    attn_kernel<<<1, 256, 0, stream>>>(feat_rel, W_rel, b_rel, attn);

    gemm_el_kernel<<<(n_src + 63) / 64, 256, 0, stream>>>(
        feat_src, W_src, b_src, attn, 0, fs, el, n_src);
    gemm_el_kernel<<<(n_dst + 63) / 64, 256, 0, stream>>>(
        feat_dst, W_dst, b_dst, attn, 16, (__half*)nullptr, er, n_dst);

    hipMemsetAsync(deg, 0, (size_t)n_dst * 4, stream);
    hipMemsetAsync(cur, 0, (size_t)n_dst * 4, stream);

    degree_kernel<<<(ne + 255) / 256, 256, 0, stream>>>(dst_idx, deg, ne);
    int nb = (n_dst + 255) / 256;
    scan1<<<nb, 256, 0, stream>>>(deg, excl, bsum, n_dst);
    scan2<<<1, 512, 0, stream>>>(bsum, nb);
    scan3<<<nb, 256, 0, stream>>>(excl, bsum, roff, n_dst);
    fill_kernel<<<(ne + 255) / 256, 256, 0, stream>>>(src_idx, dst_idx, roff, cur, csr, ne);

    agg_kernel<<<(n_dst + 3) / 4, 256, 0, stream>>>(fs, el, er, roff, deg, csr, out, n_dst);
}

// Round 2
// 505.789 us; speedup vs baseline: 1.1195x; 1.1195x over previous
//
#include <hip/hip_runtime.h>
#include <hip/hip_fp16.h>
#include <hip/hip_bf16.h>

#define SLOPE 0.2f

// ---------------------------------------------------------------------------
// attn = feat_rel @ W_rel + b_rel   (1 block, 256 threads, one col each)
// ---------------------------------------------------------------------------
__global__ void attn_kernel(const float* __restrict__ feat_rel,
                            const float* __restrict__ W_rel,
                            const float* __restrict__ b_rel,
                            float* __restrict__ attn) {
    int j = threadIdx.x;            // 0..255
    float acc = b_rel[j];
    for (int d = 0; d < 128; ++d)
        acc = fmaf(feat_rel[d], W_rel[d * 256 + j], acc);
    attn[j] = acc;
}

// ---------------------------------------------------------------------------
// Fused GEMM + per-head attention-scalar epilogue.
// Block = 256 threads, computes a 64-row x 128-col tile of f = feat@W + b.
// Thread t: rt = t>>4 (4 rows rt*4..), ct = t&15 (8 cols ct*8..): 4x8 microtile.
// Writes f (fp16, optional) and e[row][head] = sum_d f[row][h*16+d]*attn[h*32+attn_off+d].
// ---------------------------------------------------------------------------
__global__ __launch_bounds__(256) void gemm_el_kernel(
    const float* __restrict__ feat, const float* __restrict__ W,
    const float* __restrict__ bias, const float* __restrict__ attn,
    int attn_off, __half* __restrict__ f_out, float* __restrict__ e_out,
    int M)
{
    __shared__ float sA[64][68];    // [k][row], padded stride 68
    __shared__ float sW[64][128];   // [k][col]

    int t  = threadIdx.x;
    int rt = t >> 4;
    int ct = t & 15;
    int row0 = blockIdx.x * 64;

    float acc[4][8];
#pragma unroll
    for (int r = 0; r < 4; ++r)
#pragma unroll
        for (int j = 0; j < 8; ++j) acc[r][j] = 0.f;

    for (int kc = 0; kc < 2; ++kc) {
        int k0 = kc * 64;
        // stage A tile (64 rows x 64 k), transposed into sA[k][row]
        {
            int rr = t >> 4;        // 0..15
            int k4 = t & 15;        // float4 index within the 64-k chunk
#pragma unroll
            for (int i = 0; i < 4; ++i) {
                int row = rr + i * 16;
                int grow = row0 + row;
                float4 v = {0.f, 0.f, 0.f, 0.f};
                if (grow < M)
                    v = *(const float4*)(feat + (size_t)grow * 128 + k0 + k4 * 4);
                sA[k4 * 4 + 0][row] = v.x;
                sA[k4 * 4 + 1][row] = v.y;
                sA[k4 * 4 + 2][row] = v.z;
                sA[k4 * 4 + 3][row] = v.w;
            }
        }
        // stage W chunk (64 k x 128 cols)
        {
#pragma unroll
            for (int i = 0; i < 8; ++i) {
                int idx = t + i * 256;      // 0..2047 float4s
                int k = idx >> 5, j4 = idx & 31;
                *(float4*)&sW[k][j4 * 4] =
                    *(const float4*)(W + (size_t)(k0 + k) * 128 + j4 * 4);
            }
        }
        __syncthreads();
#pragma unroll 4
        for (int kk = 0; kk < 64; ++kk) {
            float4 a  = *(const float4*)&sA[kk][rt * 4];
            float4 b0 = *(const float4*)&sW[kk][ct * 8];
            float4 b1 = *(const float4*)&sW[kk][ct * 8 + 4];
            float av[4]  = {a.x, a.y, a.z, a.w};
            float bv[8]  = {b0.x, b0.y, b0.z, b0.w, b1.x, b1.y, b1.z, b1.w};
#pragma unroll
            for (int r = 0; r < 4; ++r)
#pragma unroll
                for (int j = 0; j < 8; ++j)
                    acc[r][j] = fmaf(av[r], bv[j], acc[r][j]);
        }
        __syncthreads();
    }

    // epilogue: bias, attention partial dot, fp16 store
    int h    = ct >> 1;             // head (16 cols per head, 8 cols per thread)
    int doff = (ct & 1) * 8;        // offset within head
    float bv[8], av[8];
#pragma unroll
    for (int j = 0; j < 8; ++j) {
        bv[j] = bias[ct * 8 + j];
        av[j] = attn[h * 32 + attn_off + doff + j];
    }
#pragma unroll
    for (int r = 0; r < 4; ++r) {
        int grow = row0 + rt * 4 + r;
        float part = 0.f;
#pragma unroll
        for (int j = 0; j < 8; ++j) {
            float v = acc[r][j] + bv[j];
            acc[r][j] = v;
            part = fmaf(v, av[j], part);
        }
        part += __shfl_xor(part, 1);    // combine the 2 col-threads of this head
        if (grow < M) {
            if (f_out) {
                union { __half hh[8]; float4 v4; } pk;
#pragma unroll
                for (int j = 0; j < 8; ++j) pk.hh[j] = __float2half(acc[r][j]);
                *(float4*)(f_out + (size_t)grow * 128 + ct * 8) = pk.v4;
            }
            if ((ct & 1) == 0)
                e_out[(size_t)grow * 8 + h] = part;
        }
    }
}

// ---------------------------------------------------------------------------
// CSR build
// ---------------------------------------------------------------------------
__global__ void degree_kernel(const int* __restrict__ dst_idx,
                              int* __restrict__ deg, int ne) {
    int e = blockIdx.x * 256 + threadIdx.x;
    if (e < ne) atomicAdd(&deg[dst_idx[e]], 1);
}

__global__ void scan1(const int* __restrict__ deg, int* __restrict__ excl,
                      int* __restrict__ bsum, int n) {
    __shared__ int tmp[256];
    int t = threadIdx.x;
    int i = blockIdx.x * 256 + t;
    int v = (i < n) ? deg[i] : 0;
    tmp[t] = v;
    __syncthreads();
    for (int off = 1; off < 256; off <<= 1) {
        int x = 0;
        if (t >= off) x = tmp[t - off];
        __syncthreads();
        tmp[t] += x;
        __syncthreads();
    }
    if (i < n) excl[i] = tmp[t] - v;
    if (t == 255) bsum[blockIdx.x] = tmp[255];
}

__global__ void scan2(int* __restrict__ bsum, int nb) {
    __shared__ int tmp[512];
    int t = threadIdx.x;
    int v = (t < nb) ? bsum[t] : 0;
    tmp[t] = v;
    __syncthreads();
    for (int off = 1; off < 512; off <<= 1) {
        int x = 0;
        if (t >= off) x = tmp[t - off];
        __syncthreads();
        tmp[t] += x;
        __syncthreads();
    }
    if (t < nb) bsum[t] = tmp[t] - v;   // exclusive block offsets
}

__global__ void scan3(const int* __restrict__ excl, const int* __restrict__ bsum,
                      int* __restrict__ roff, int n) {
    int i = blockIdx.x * 256 + threadIdx.x;
    if (i < n) roff[i] = excl[i] + bsum[blockIdx.x];
}

// fill: build CSR src list AND precompute per-(edge,head) softmax weights
// w[p][h] = exp(leaky(el[src][h] + er[dst][h])) stored in CSR position order.
__global__ void fill_kernel(const int* __restrict__ src_idx,
                            const int* __restrict__ dst_idx,
                            const int* __restrict__ roff, int* __restrict__ cur,
                            const float* __restrict__ el,
                            const float* __restrict__ er,
                            int* __restrict__ csr,
                            __hip_bfloat16* __restrict__ wE, int ne) {
    int e = blockIdx.x * 256 + threadIdx.x;
    if (e >= ne) return;
    int s = src_idx[e];
    int d = dst_idx[e];
    int p = roff[d] + atomicAdd(&cur[d], 1);
    csr[p] = s;

    float4 l0 = *(const float4*)(el + (size_t)s * 8);
    float4 l1 = *(const float4*)(el + (size_t)s * 8 + 4);
    float4 r0 = *(const float4*)(er + (size_t)d * 8);
    float4 r1 = *(const float4*)(er + (size_t)d * 8 + 4);
    float ev[8] = {l0.x + r0.x, l0.y + r0.y, l0.z + r0.z, l0.w + r0.w,
                   l1.x + r1.x, l1.y + r1.y, l1.z + r1.z, l1.w + r1.w};
    union { __hip_bfloat16 wh[8]; float4 v4; } pk;
#pragma unroll
    for (int h = 0; h < 8; ++h) {
        float x = ev[h];
        x = (x < 0.f) ? SLOPE * x : x;
        pk.wh[h] = __float2bfloat16(__expf(x));
    }
    *(float4*)(wE + (size_t)p * 8) = pk.v4;   // 16B aligned (p*8 bf16)
}

// ---------------------------------------------------------------------------
// Aggregation: one wave per dst node. lane owns dims 2l,2l+1; head = l>>3.
// out[dst] = sum_e w_e * fs[src_e] / sum_e w_e   (== edge_softmax + u_mul_e + sum)
// 4-way unrolled: 4 independent fs gathers in flight per wave.
// ---------------------------------------------------------------------------
__global__ __launch_bounds__(256) void agg_kernel(
    const __half* __restrict__ fs, const __hip_bfloat16* __restrict__ wE,
    const int* __restrict__ roff, const int* __restrict__ deg,
    const int* __restrict__ csr, float* __restrict__ out, int n)
{
    int node = blockIdx.x * 4 + (threadIdx.x >> 6);
    if (node >= n) return;
    int lane = threadIdx.x & 63;
    int h = lane >> 3;
    int start = roff[node];
    int d = deg[node];

    float accx = 0.f, accy = 0.f, wsum = 0.f;
    int i = 0;
    for (; i + 4 <= d; i += 4) {
        int s0 = csr[start + i + 0];
        int s1 = csr[start + i + 1];
        int s2 = csr[start + i + 2];
        int s3 = csr[start + i + 3];
        float w0 = __bfloat162float(wE[(size_t)(start + i + 0) * 8 + h]);
        float w1 = __bfloat162float(wE[(size_t)(start + i + 1) * 8 + h]);
        float w2 = __bfloat162float(wE[(size_t)(start + i + 2) * 8 + h]);
        float w3 = __bfloat162float(wE[(size_t)(start + i + 3) * 8 + h]);
        __half2 f0 = *(const __half2*)(fs + (size_t)s0 * 128 + 2 * lane);
        __half2 f1 = *(const __half2*)(fs + (size_t)s1 * 128 + 2 * lane);
        __half2 f2 = *(const __half2*)(fs + (size_t)s2 * 128 + 2 * lane);
        __half2 f3 = *(const __half2*)(fs + (size_t)s3 * 128 + 2 * lane);
        float2 a0 = __half22float2(f0);
        float2 a1 = __half22float2(f1);
        float2 a2 = __half22float2(f2);
        float2 a3 = __half22float2(f3);
        accx = fmaf(w0, a0.x, accx); accy = fmaf(w0, a0.y, accy);
        accx = fmaf(w1, a1.x, accx); accy = fmaf(w1, a1.y, accy);
        accx = fmaf(w2, a2.x, accx); accy = fmaf(w2, a2.y, accy);
        accx = fmaf(w3, a3.x, accx); accy = fmaf(w3, a3.y, accy);
        wsum += (w0 + w1) + (w2 + w3);
    }
    for (; i < d; ++i) {
        int s = csr[start + i];
        float wgt = __bfloat162float(wE[(size_t)(start + i) * 8 + h]);
        __half2 f2v = *(const __half2*)(fs + (size_t)s * 128 + 2 * lane);
        float2 ff = __half22float2(f2v);
        accx = fmaf(wgt, ff.x, accx);
        accy = fmaf(wgt, ff.y, accy);
        wsum += wgt;
    }
    float inv = (d > 0) ? 1.0f / wsum : 0.f;
    float2 o;
    o.x = accx * inv;
    o.y = accy * inv;
    *(float2*)(out + (size_t)node * 128 + 2 * lane) = o;
}

// ---------------------------------------------------------------------------
extern "C" void kernel_launch(void* const* d_in, const int* in_sizes, int n_in,
                              void* d_out, int out_size, void* d_ws, size_t ws_size,
                              hipStream_t stream) {
    const float* feat_src = (const float*)d_in[0];
    const float* feat_dst = (const float*)d_in[1];
    const float* feat_rel = (const float*)d_in[2];
    const float* W_src    = (const float*)d_in[3];
    const float* b_src    = (const float*)d_in[4];
    const float* W_dst    = (const float*)d_in[5];
    const float* b_dst    = (const float*)d_in[6];
    const float* W_rel    = (const float*)d_in[7];
    const float* b_rel    = (const float*)d_in[8];
    const int*   src_idx  = (const int*)d_in[9];
    const int*   dst_idx  = (const int*)d_in[10];
    float* out = (float*)d_out;

    int n_src = in_sizes[0] / 128;
    int n_dst = in_sizes[1] / 128;
    int ne    = in_sizes[9];

    char* w = (char*)d_ws;
    auto alloc = [&](size_t b) { char* p = w; w += (b + 255) & ~(size_t)255; return p; };
    __half* fs   = (__half*)alloc((size_t)n_src * 128 * 2);
    float*  el   = (float*)alloc((size_t)n_src * 8 * 4);
    float*  er   = (float*)alloc((size_t)n_dst * 8 * 4);
    float*  attn = (float*)alloc(256 * 4);
    int*    deg  = (int*)alloc((size_t)n_dst * 4);
    int*    cur  = (int*)alloc((size_t)n_dst * 4);
    int*    excl = (int*)alloc((size_t)n_dst * 4);
    int*    bsum = (int*)alloc(512 * 4);
    int*    roff = (int*)alloc((size_t)n_dst * 4);
    int*    csr  = (int*)alloc((size_t)ne * 4);
    __hip_bfloat16* wE = (__hip_bfloat16*)alloc((size_t)ne * 8 * 2);

    attn_kernel<<<1, 256, 0, stream>>>(feat_rel, W_rel, b_rel, attn);

    gemm_el_kernel<<<(n_src + 63) / 64, 256, 0, stream>>>(
        feat_src, W_src, b_src, attn, 0, fs, el, n_src);
    gemm_el_kernel<<<(n_dst + 63) / 64, 256, 0, stream>>>(
        feat_dst, W_dst, b_dst, attn, 16, (__half*)nullptr, er, n_dst);

    hipMemsetAsync(deg, 0, (size_t)n_dst * 4, stream);
    hipMemsetAsync(cur, 0, (size_t)n_dst * 4, stream);

    degree_kernel<<<(ne + 255) / 256, 256, 0, stream>>>(dst_idx, deg, ne);
    int nb = (n_dst + 255) / 256;
    scan1<<<nb, 256, 0, stream>>>(deg, excl, bsum, n_dst);
    scan2<<<1, 512, 0, stream>>>(bsum, nb);
    scan3<<<nb, 256, 0, stream>>>(excl, bsum, roff, n_dst);
    fill_kernel<<<(ne + 255) / 256, 256, 0, stream>>>(
        src_idx, dst_idx, roff, cur, el, er, csr, wE, ne);

    agg_kernel<<<(n_dst + 3) / 4, 256, 0, stream>>>(fs, wE, roff, deg, csr, out, n_dst);
}